// Round 1
// baseline (855.186 us; speedup 1.0000x reference)
//
#include <hip/hip_runtime.h>

// Fused MLP: o = silu(x @ w1) @ w2, per head.
// H=16, N=8192, D=256, I=1024, fp32 in/out, bf16 MFMA compute (threshold allows).
// Block = 512 threads (8 waves), tile = 128 rows x full D=256 output,
// I processed in 16 chunks of 64. x A-frags live in registers for all chunks;
// w1/w2 chunks staged transposed (k-contiguous) in LDS; h round-trips LDS
// (MFMA C-layout -> A-layout transform, per m120).

#define Hn 16
#define Nn 8192
#define Dn 256
#define In 1024
#define TN 128
#define IC 64
#define NCH (In / IC)
#define BS 512

// LDS row strides (bf16 elems), padded: stride*2 must be multiple of 16 B,
// and not a multiple of 128 B to break bank aliasing (264*2=528, 72*2=144).
#define W1S 264
#define W2S 72
#define HS  72

typedef __bf16 bf16x8 __attribute__((ext_vector_type(8)));
typedef unsigned short ushortx8 __attribute__((ext_vector_type(8)));
typedef float floatx4 __attribute__((ext_vector_type(4)));

union FragU { ushortx8 u; bf16x8 b; };

// fp32 -> bf16 bits, round-to-nearest-even (finite inputs only)
__device__ __forceinline__ unsigned short f2bf(float f) {
  unsigned u = __builtin_bit_cast(unsigned, f);
  u += 0x7FFFu + ((u >> 16) & 1u);
  return (unsigned short)(u >> 16);
}

__global__ __launch_bounds__(BS, 2) void fused_mlp(
    const float* __restrict__ x, const float* __restrict__ w1,
    const float* __restrict__ w2, float* __restrict__ out) {
  __shared__ __align__(16) unsigned short lds_w1[IC * W1S];  // [i'][d]  (B of GEMM1, k=d contiguous)
  __shared__ __align__(16) unsigned short lds_w2[Dn * W2S];  // [d][i']  (B of GEMM2, k=i' contiguous)
  __shared__ __align__(16) unsigned short lds_h[TN * HS];    // [n][i']  (A of GEMM2, k=i' contiguous)

  const int tid  = threadIdx.x;
  const int wid  = tid >> 6;   // 0..7
  const int lane = tid & 63;
  const int quad = lane >> 4;  // 0..3
  const int l16  = lane & 15;

  const int bid = blockIdx.x;
  const int h   = bid >> 6;          // 64 consecutive blocks share a head -> weight L2/L3 reuse
  const int n0  = (bid & 63) * TN;

  const float* xg  = x   + (size_t)h * Nn * Dn + (size_t)n0 * Dn;
  const float* w1g = w1  + (size_t)h * Dn * In;
  const float* w2g = w2  + (size_t)h * In * Dn;
  float*       og  = out + (size_t)h * Nn * Dn + (size_t)n0 * Dn;

  // --- x A-fragments for this wave's 16-row strip (local rows 16*wid..+15) ---
  // A layout (verified m120): A[m = lane&15][k = quad*8 + j], j=0..7
  FragU xa[8];
  {
    const float* xr = xg + (size_t)(16 * wid + l16) * Dn + quad * 8;
#pragma unroll
    for (int s = 0; s < 8; ++s) {  // kstep s covers k = 32s..32s+31
      floatx4 v0 = *(const floatx4*)(xr + 32 * s);
      floatx4 v1 = *(const floatx4*)(xr + 32 * s + 4);
#pragma unroll
      for (int j = 0; j < 4; ++j) {
        xa[s].u[j]     = f2bf(v0[j]);
        xa[s].u[4 + j] = f2bf(v1[j]);
      }
    }
  }

  const floatx4 fzero = {0.f, 0.f, 0.f, 0.f};
  floatx4 oacc[16];
#pragma unroll
  for (int t = 0; t < 16; ++t) oacc[t] = fzero;

  for (int c = 0; c < NCH; ++c) {
    __syncthreads();  // previous chunk's LDS reads done before restage

    // --- stage w1 chunk: global [d][64 cols] -> lds transposed [i'][d] ---
#pragma unroll
    for (int it = 0; it < 8; ++it) {
      int idx = it * BS + tid;
      int d   = idx >> 4;          // 0..255
      int i4  = (idx & 15) * 4;    // 0..60
      floatx4 v = *(const floatx4*)(w1g + (size_t)d * In + c * IC + i4);
#pragma unroll
      for (int j = 0; j < 4; ++j) lds_w1[(i4 + j) * W1S + d] = f2bf(v[j]);
    }
    // --- stage w2 chunk: global [i'][256 cols] -> lds transposed [d][i'] ---
#pragma unroll
    for (int it = 0; it < 8; ++it) {
      int idx = it * BS + tid;
      int ip  = idx >> 6;          // 0..63
      int d4  = (idx & 63) * 4;    // 0..252
      floatx4 v = *(const floatx4*)(w2g + (size_t)(c * IC + ip) * Dn + d4);
#pragma unroll
      for (int j = 0; j < 4; ++j) lds_w2[(d4 + j) * W2S + ip] = f2bf(v[j]);
    }
    __syncthreads();

    // --- GEMM1: z[16*wid..+15][0..63] += x_strip @ w1_chunk, K = 256 ---
    floatx4 zacc[4];
#pragma unroll
    for (int t = 0; t < 4; ++t) zacc[t] = fzero;
#pragma unroll
    for (int s = 0; s < 8; ++s) {
#pragma unroll
      for (int t = 0; t < 4; ++t) {
        FragU b;  // B[k=32s+quad*8+j][n=16t+l16] from w1t[n][k]
        b.u = *(const ushortx8*)(&lds_w1[(16 * t + l16) * W1S + 32 * s + quad * 8]);
        zacc[t] = __builtin_amdgcn_mfma_f32_16x16x32_bf16(xa[s].b, b.b, zacc[t], 0, 0, 0);
      }
    }

    // --- silu, C-layout (row = quad*4+r, col = l16) -> lds_h A-layout ---
#pragma unroll
    for (int t = 0; t < 4; ++t) {
#pragma unroll
      for (int r = 0; r < 4; ++r) {
        float z  = zacc[t][r];
        float hv = z / (1.f + __expf(-z));
        lds_h[(16 * wid + quad * 4 + r) * HS + 16 * t + l16] = f2bf(hv);
      }
    }
    __syncthreads();

    // --- GEMM2: oacc[16*wid..+15][0..255] += h_strip @ w2_chunk, K = 64 ---
#pragma unroll
    for (int s = 0; s < 2; ++s) {
      FragU a;  // A[m=l16][k=32s+quad*8+j] from lds_h
      a.u = *(const ushortx8*)(&lds_h[(16 * wid + l16) * HS + 32 * s + quad * 8]);
#pragma unroll
      for (int t = 0; t < 16; ++t) {
        FragU b;  // B[k][n=16t+l16] from w2t[n][k]
        b.u = *(const ushortx8*)(&lds_w2[(16 * t + l16) * W2S + 32 * s + quad * 8]);
        oacc[t] = __builtin_amdgcn_mfma_f32_16x16x32_bf16(a.b, b.b, oacc[t], 0, 0, 0);
      }
    }
  }

  // --- epilogue: C-layout scatter, fp32 stores ---
#pragma unroll
  for (int t = 0; t < 16; ++t) {
#pragma unroll
    for (int r = 0; r < 4; ++r) {
      og[(size_t)(16 * wid + quad * 4 + r) * Dn + 16 * t + l16] = oacc[t][r];
    }
  }
}

extern "C" void kernel_launch(void* const* d_in, const int* in_sizes, int n_in,
                              void* d_out, int out_size, void* d_ws, size_t ws_size,
                              hipStream_t stream) {
  const float* x  = (const float*)d_in[0];
  const float* w1 = (const float*)d_in[1];
  const float* w2 = (const float*)d_in[2];
  float* out      = (float*)d_out;
  (void)in_sizes; (void)n_in; (void)out_size; (void)d_ws; (void)ws_size;
  dim3 grid(Hn * (Nn / TN));  // 1024 blocks
  dim3 block(BS);             // 512 threads = 8 waves
  hipLaunchKernelGGL(fused_mlp, grid, block, 0, stream, x, w1, w2, out);
}

// Round 2
// 524.109 us; speedup vs baseline: 1.6317x; 1.6317x over previous
//
#include <hip/hip_runtime.h>

// Fused MLP: o = silu(x @ w1) @ w2 per head. H=16, N=8192, D=256, I=1024, fp32.
// bf16 MFMA (32x32x16). Block = 512 thr (8 waves), tile = 128 rows x D=256.
// GEMM1 computes z^T = w1^T x^T (A = lds_w1t[i][d], B = x in registers).
// GEMM2 computes o^T = w2^T h^T (A = lds_w2t[d][i], B = lds_h[n][i]).
// All LDS traffic is b128/b64 with bank-uniform lane mappings (pad strides
// 264/72: lane word-stride === 4 mod 32). Weight staging double-buffered;
// next chunk's global loads issued into regs after sync1 (latency hidden).

#define Hn 16
#define Nn 8192
#define Dn 256
#define In 1024
#define TN 128
#define IC 64
#define NCH (In / IC)
#define BS 512

#define W1S 264  // ushorts per lds_w1t row (256 + 8 pad), mult of 8
#define W2S 72   // (64 + 8)
#define HS  72

typedef __bf16 bf16x8 __attribute__((ext_vector_type(8)));
typedef unsigned short ushortx8 __attribute__((ext_vector_type(8)));
typedef unsigned short ushortx4 __attribute__((ext_vector_type(4)));
typedef float floatx4 __attribute__((ext_vector_type(4)));
typedef float floatx16 __attribute__((ext_vector_type(16)));

union Frag8 { ushortx8 u; bf16x8 b; };

__device__ __forceinline__ unsigned short f2bf(float f) {
  unsigned u = __builtin_bit_cast(unsigned, f);
  u += 0x7FFFu + ((u >> 16) & 1u);
  return (unsigned short)(u >> 16);
}

__global__ __launch_bounds__(BS, 2) void fused_mlp(
    const float* __restrict__ x, const float* __restrict__ w1,
    const float* __restrict__ w2, float* __restrict__ out) {
  // 2*33792 + 2*36864 + 18432 = 159744 B <= 160 KiB
  __shared__ __align__(16) unsigned short lds_w1t[2][IC * W1S];  // [i][d] = w1^T chunk
  __shared__ __align__(16) unsigned short lds_w2t[2][Dn * W2S];  // [d][i] = w2^T chunk
  __shared__ __align__(16) unsigned short lds_h[TN * HS];        // [n][i] = h tile

  const int tid  = threadIdx.x;
  const int wid  = tid >> 6;
  const int l    = tid & 63;
  const int half = l >> 5;   // 0..1
  const int l31  = l & 31;

  // GEMM1 wave tile: 32 i x 32 n over z^T[64][128]
  const int ti = wid & 1;   // i-tile
  const int tn = wid >> 1;  // n-tile 0..3
  // GEMM2 wave macro-tile: 64 d x 64 n over o^T[256][128]
  const int td  = wid & 3;
  const int tn2 = wid >> 2;
  // staging lane roles
  const int s_kg = l >> 4;  // w1: d8-subgroup 0..3
  const int s_cg = l & 15;  // w1: i-group (4 i each)
  const int s_d4 = l >> 3;  // w2: d-group (4 d each)
  const int s_i8 = l & 7;   // w2: i8-block 0..7

  const int bid = blockIdx.x;
  const int h   = bid >> 6;
  const int n0  = (bid & 63) * TN;

  const float* xg  = x   + (size_t)h * Nn * Dn + (size_t)n0 * Dn;
  const float* w1g = w1  + (size_t)h * Dn * In;
  const float* w2g = w2  + (size_t)h * In * Dn;
  float*       og  = out + (size_t)h * Nn * Dn + (size_t)n0 * Dn;

  // --- x -> registers as GEMM1 B-frags (x^T B-operand) ---
  // B-frag lane holds x[n = 32*tn + l31][k = 16*s + half*8 + j], j=0..7
  Frag8 xa[16];
  {
    const float* xr = xg + (size_t)(32 * tn + l31) * Dn + half * 8;
#pragma unroll
    for (int s = 0; s < 16; ++s) {
      floatx4 v0 = *(const floatx4*)(xr + 16 * s);
      floatx4 v1 = *(const floatx4*)(xr + 16 * s + 4);
#pragma unroll
      for (int j = 0; j < 4; ++j) {
        xa[s].u[j]     = f2bf(v0[j]);
        xa[s].u[4 + j] = f2bf(v1[j]);
      }
    }
  }

  // --- staging registers (next chunk's weights) ---
  floatx4 r1[8], r2[8];
  const float* p1 = w1g + (size_t)(wid * 32 + s_kg * 8) * In + s_cg * 4;
  const float* p2base = w2g + (size_t)(wid * 32 + s_d4 * 4);

#define LOAD_STAGE(c)                                                       \
  {                                                                         \
    const float* q1 = p1 + (c) * IC;                                        \
    _Pragma("unroll") for (int r = 0; r < 8; ++r)                           \
        r1[r] = *(const floatx4*)(q1 + (size_t)r * In);                     \
    const float* q2 = p2base + (size_t)((c) * IC + s_i8 * 8) * Dn;          \
    _Pragma("unroll") for (int r = 0; r < 8; ++r)                           \
        r2[r] = *(const floatx4*)(q2 + (size_t)r * Dn);                     \
  }

  LOAD_STAGE(0);

  floatx16 oacc[2][2];
#pragma unroll
  for (int a = 0; a < 2; ++a)
#pragma unroll
    for (int b = 0; b < 2; ++b)
#pragma unroll
      for (int e = 0; e < 16; ++e) oacc[a][b][e] = 0.f;

  for (int c = 0; c < NCH; ++c) {
    const int buf = c & 1;

    // --- staging regs -> LDS (transposed, b128, bank-uniform) ---
#pragma unroll
    for (int j = 0; j < 4; ++j) {
      Frag8 t;
#pragma unroll
      for (int r = 0; r < 8; ++r) t.u[r] = f2bf(r1[r][j]);
      *(ushortx8*)&lds_w1t[buf][(s_cg * 4 + j) * W1S + (wid * 4 + s_kg) * 8] = t.u;
    }
#pragma unroll
    for (int j = 0; j < 4; ++j) {
      Frag8 t;
#pragma unroll
      for (int r = 0; r < 8; ++r) t.u[r] = f2bf(r2[r][j]);
      *(ushortx8*)&lds_w2t[buf][(wid * 32 + s_d4 * 4 + j) * W2S + s_i8 * 8] = t.u;
    }
    __syncthreads();

    if (c + 1 < NCH) LOAD_STAGE(c + 1);  // latency hidden behind G1+G2

    // --- GEMM1: z^T[32*ti..][32*tn..] = w1^T x^T, K = 256 ---
    floatx16 zacc;
#pragma unroll
    for (int e = 0; e < 16; ++e) zacc[e] = 0.f;
#pragma unroll
    for (int s = 0; s < 16; ++s) {
      Frag8 a;
      a.u = *(const ushortx8*)&lds_w1t[buf][(32 * ti + l31) * W1S + (2 * s + half) * 8];
      zacc = __builtin_amdgcn_mfma_f32_32x32x16_bf16(a.b, xa[s].b, zacc, 0, 0, 0);
    }

    // --- silu, z^T C-layout: lane holds rows i = (reg&3)+8*(reg>>2)+4*half,
    //     col n = l31  ->  4 consecutive i at fixed n: b64 writes to h[n][i] ---
#pragma unroll
    for (int rg = 0; rg < 4; ++rg) {
      ushortx4 t;
#pragma unroll
      for (int r = 0; r < 4; ++r) {
        float z = zacc[4 * rg + r];
        t[r] = f2bf(z / (1.f + __expf(-z)));
      }
      *(ushortx4*)&lds_h[(32 * tn + l31) * HS + 32 * ti + 8 * rg + 4 * half] = t;
    }
    __syncthreads();

    // --- GEMM2: o^T += w2^T h^T, K = 64 (4 ksteps of 16) ---
#pragma unroll
    for (int s = 0; s < 4; ++s) {
      Frag8 A0, A1, B0, B1;
      const int kk = (2 * s + half) * 8;
      A0.u = *(const ushortx8*)&lds_w2t[buf][(64 * td + l31) * W2S + kk];
      A1.u = *(const ushortx8*)&lds_w2t[buf][(64 * td + 32 + l31) * W2S + kk];
      B0.u = *(const ushortx8*)&lds_h[(64 * tn2 + l31) * HS + kk];
      B1.u = *(const ushortx8*)&lds_h[(64 * tn2 + 32 + l31) * HS + kk];
      oacc[0][0] = __builtin_amdgcn_mfma_f32_32x32x16_bf16(A0.b, B0.b, oacc[0][0], 0, 0, 0);
      oacc[0][1] = __builtin_amdgcn_mfma_f32_32x32x16_bf16(A0.b, B1.b, oacc[0][1], 0, 0, 0);
      oacc[1][0] = __builtin_amdgcn_mfma_f32_32x32x16_bf16(A1.b, B0.b, oacc[1][0], 0, 0, 0);
      oacc[1][1] = __builtin_amdgcn_mfma_f32_32x32x16_bf16(A1.b, B1.b, oacc[1][1], 0, 0, 0);
    }
  }

  // --- epilogue: o^T C-layout -> out[n][d], 4 consecutive d = float4 ---
#pragma unroll
  for (int cd = 0; cd < 2; ++cd) {
#pragma unroll
    for (int cn = 0; cn < 2; ++cn) {
      const int n = 64 * tn2 + 32 * cn + l31;
#pragma unroll
      for (int rg = 0; rg < 4; ++rg) {
        floatx4 v;
#pragma unroll
        for (int r = 0; r < 4; ++r) v[r] = oacc[cd][cn][4 * rg + r];
        const int d0 = 64 * td + 32 * cd + 8 * rg + 4 * half;
        *(floatx4*)(og + (size_t)n * Dn + d0) = v;
      }
    }
  }
}

extern "C" void kernel_launch(void* const* d_in, const int* in_sizes, int n_in,
                              void* d_out, int out_size, void* d_ws, size_t ws_size,
                              hipStream_t stream) {
  const float* x  = (const float*)d_in[0];
  const float* w1 = (const float*)d_in[1];
  const float* w2 = (const float*)d_in[2];
  float* out      = (float*)d_out;
  (void)in_sizes; (void)n_in; (void)out_size; (void)d_ws; (void)ws_size;
  hipLaunchKernelGGL(fused_mlp, dim3(Hn * (Nn / TN)), dim3(BS), 0, stream,
                     x, w1, w2, out);
}